// Round 7
// baseline (7961.573 us; speedup 1.0000x reference)
//
#include <hip/hip_runtime.h>
#include <hip/hip_bf16.h>

// R7 = R6 + register pinning of the persistent Whh B-fragments.
// R6 post-mortem: compiler rematerialized/spilled bfr -> ~1 MB/step/CU L2 traffic
// (7.5 us/step, matching L2 BW). Empty `asm volatile("" : "+v"(frag))` makes each
// fragment an opaque register-resident value: no remat, no sinking into the loop.
// Structure: 8 blocks x 1024 threads (one per 16-sample group); wave w owns cols
// [w*32, w*32+32); h exchange intra-block via double-buffered frag-major LDS.

typedef __attribute__((ext_vector_type(8))) short bf16x8;
typedef __attribute__((ext_vector_type(4))) float f32x4;

#define T_STEPS 512
#define NBATCH  128
#define HID     512
#define INSZ    256
#define HB      8192   // shorts per LDS h buffer (16 samples x 512 cols, frag-major)

static __device__ __forceinline__ float bf2f(__hip_bfloat16 v) { return __bfloat162float(v); }
static __device__ __forceinline__ __hip_bfloat16 f2bf(float v) { return __float2bfloat16(v); }

union BF8 { bf16x8 v; unsigned short u[8]; };
static __device__ __forceinline__ unsigned short f2bfbits(float x) {
    __hip_bfloat16 b = __float2bfloat16(x);
    return *reinterpret_cast<unsigned short*>(&b);
}
static __device__ __forceinline__ float loadE(const void* p, size_t i, bool f32) {
    return f32 ? ((const float*)p)[i] : bf2f(((const __hip_bfloat16*)p)[i]);
}
// tanh(x) = 1 - 2/(e^{2x}+1); exp over/underflow saturates correctly to +-1.
static __device__ __forceinline__ float fast_tanh(float x) {
    float e = __expf(2.f * x);
    float r = __builtin_amdgcn_rcpf(e + 1.f);
    return 1.f - 2.f * r;
}

// ---------------- dtype probe: even uint16s of fp32 data are random mantissa halves
__global__ void detect_dtype(const unsigned short* __restrict__ x, unsigned int* __restrict__ dflag) {
    if (threadIdx.x == 0 && blockIdx.x == 0) {
        int sane = 0;
        for (int i = 0; i < 64; ++i) {
            unsigned short v = x[2 * i];
            unsigned int e = (v >> 7) & 0xFF;
            if (v == 0 || (e >= 0x60 && e <= 0x9F)) ++sane;
        }
        *dflag = (sane >= 48) ? 0u : 1u;  // 0 = bf16 data, 1 = fp32 data
    }
}

// ---------------- GEMM: out[M][N] = A[M][K] @ W[N][K]^T + b1[N] (+ b2[N])
__global__ __launch_bounds__(256, 4) void gemm_bt64(
    const void* __restrict__ A, const void* __restrict__ W,
    const void* __restrict__ b1, const void* __restrict__ b2,
    void* __restrict__ out, int M, int N, int K,
    const int* __restrict__ lengths, const unsigned int* __restrict__ dflag,
    int aIsOrig, int outIsOutput)
{
    const int r0 = blockIdx.y * 64;
    if (lengths) {  // rows are (t*128+n); a 64-row tile is one t, n0 in {0,64}; sorted desc.
        int t = r0 >> 7, n0 = r0 & 127;
        if (lengths[n0] <= t) return;
    }
    const bool f32 = *dflag != 0;
    const int c0 = blockIdx.x * 64;
    __shared__ short As[64 * 32];
    __shared__ short Bs[64 * 32];
    const int tid = threadIdx.x;
    const int lane = tid & 63, wave = tid >> 6;
    const int lrow = tid >> 2, lk = (tid & 3) * 8;
    const int q = (lane >> 4) & 3, l15 = lane & 15;

    f32x4 z = {0.f, 0.f, 0.f, 0.f};
    f32x4 acc[4];
#pragma unroll
    for (int m = 0; m < 4; ++m) acc[m] = z;

    for (int kk = 0; kk < K; kk += 32) {
        if (aIsOrig && f32) {
            const float* f = (const float*)A + (size_t)(r0 + lrow) * K + kk + lk;
            BF8 u;
#pragma unroll
            for (int i = 0; i < 8; ++i) u.u[i] = f2bfbits(f[i]);
            *(bf16x8*)&As[lrow * 32 + lk] = u.v;
        } else {
            *(bf16x8*)&As[lrow * 32 + lk] =
                *(const bf16x8*)((const __hip_bfloat16*)A + (size_t)(r0 + lrow) * K + kk + lk);
        }
        if (f32) {
            const float* f = (const float*)W + (size_t)(c0 + lrow) * K + kk + lk;
            BF8 u;
#pragma unroll
            for (int i = 0; i < 8; ++i) u.u[i] = f2bfbits(f[i]);
            *(bf16x8*)&Bs[lrow * 32 + lk] = u.v;
        } else {
            *(bf16x8*)&Bs[lrow * 32 + lk] =
                *(const bf16x8*)((const __hip_bfloat16*)W + (size_t)(c0 + lrow) * K + kk + lk);
        }
        __syncthreads();
        bf16x8 bfrag = *(const bf16x8*)&Bs[(wave * 16 + l15) * 32 + q * 8];
#pragma unroll
        for (int m = 0; m < 4; ++m) {
            bf16x8 afrag = *(const bf16x8*)&As[(m * 16 + l15) * 32 + q * 8];
            acc[m] = __builtin_amdgcn_mfma_f32_16x16x32_bf16(afrag, bfrag, acc[m], 0, 0, 0);
        }
        __syncthreads();
    }
    const int col = c0 + wave * 16 + l15;
    float bias = loadE(b1, col, f32) + (b2 ? loadE(b2, col, f32) : 0.f);
#pragma unroll
    for (int m = 0; m < 4; ++m) {
#pragma unroll
        for (int r = 0; r < 4; ++r) {
            int row = r0 + m * 16 + q * 4 + r;
            float v = acc[m][r] + bias;
            if (outIsOutput && f32) ((float*)out)[(size_t)row * N + col] = v;
            else ((__hip_bfloat16*)out)[(size_t)row * N + col] = f2bf(v);
        }
    }
}

// ---------------- recurrence: 8 blocks (one per 16-sample group), 1024 threads.
__global__ __launch_bounds__(1024, 1) void rnn_recur(
    const __hip_bfloat16* __restrict__ xp,    // [T*128][512] bf16 (ws)
    const void* __restrict__ Whh,             // [512][512] orig dtype
    const void* __restrict__ h0all,           // [2][128][512] orig dtype
    int layer,
    const int* __restrict__ lengths,          // [128] sorted desc
    __hip_bfloat16* __restrict__ out0,        // [T*128][512] bf16 or nullptr
    void* __restrict__ hout,                  // d_out base; final h at elem houtOff
    int houtOff,
    __hip_bfloat16* __restrict__ hfbf,        // [128][512] final h bf16 (logits input)
    const unsigned int* __restrict__ dflag)
{
    const int gb = blockIdx.x;
    const int s0 = gb * 16;
    const int tid = threadIdx.x, lane = tid & 63, wave = tid >> 6;
    const int q = (lane >> 4) & 3, l15 = lane & 15;
    const int colBase = wave * 32;            // this wave's 32 output columns
    const bool f32 = *dflag != 0;
    const size_t h0base = (size_t)layer * NBATCH * HID;
    __shared__ short hlds[2 * HB];            // 32 KB

    // persistent B fragments: Whh[j][k], j in wave's 32 cols, full K (128 regs).
    // PINNED via opaque asm so the compiler cannot remat/sink the loads (R6 bug).
    bf16x8 bfr[2][16];
#pragma unroll
    for (int tau = 0; tau < 2; ++tau)
#pragma unroll
        for (int c = 0; c < 16; ++c) {
            if (f32) {
                const float* f = (const float*)Whh + (size_t)(colBase + tau * 16 + l15) * HID + c * 32 + q * 8;
                BF8 u;
#pragma unroll
                for (int i = 0; i < 8; ++i) u.u[i] = f2bfbits(f[i]);
                bfr[tau][c] = u.v;
            } else {
                bfr[tau][c] = *(const bf16x8*)((const __hip_bfloat16*)Whh +
                    (size_t)(colBase + tau * 16 + l15) * HID + c * 32 + q * 8);
            }
            asm volatile("" : "+v"(bfr[tau][c]));  // pin: opaque reg-resident def
        }

    int len_r[4];
#pragma unroll
    for (int r = 0; r < 4; ++r) len_r[r] = lengths[s0 + q * 4 + r];

    float cur[2][4];  // owned h: sample q*4+r, col colBase + tau*16 + l15
#pragma unroll
    for (int tau = 0; tau < 2; ++tau)
#pragma unroll
        for (int r = 0; r < 4; ++r)
            cur[tau][r] = loadE(h0all, h0base + (size_t)(s0 + q * 4 + r) * HID + colBase + tau * 16 + l15, f32);

    // stage S_0 into LDS buf 0 (frag-major): thread covers sample sr, cols cb8..cb8+7
    {
        const int sr = tid >> 6, cb8 = (tid & 63) * 8;
        BF8 u0;
#pragma unroll
        for (int i = 0; i < 8; ++i)
            u0.u[i] = f2bfbits(loadE(h0all, h0base + (size_t)(s0 + sr) * HID + cb8 + i, f32));
        *(bf16x8*)&hlds[(((cb8 >> 3) * 16) + sr) * 8] = u0.v;
    }
    __syncthreads();

    const int Tg = lengths[s0];   // group max length (sorted desc)

    // preload xp for t=0
    float xv[2][4];
    {
        const __hip_bfloat16* xprow = xp + (size_t)s0 * HID;
#pragma unroll
        for (int tau = 0; tau < 2; ++tau)
#pragma unroll
            for (int r = 0; r < 4; ++r)
                xv[tau][r] = bf2f(xprow[(size_t)(q * 4 + r) * HID + colBase + tau * 16 + l15]);
    }

    for (int t = 0; t < Tg; ++t) {
        const int cb_ = t & 1, nb = (t + 1) & 1;
        const short* hrd = &hlds[cb_ * HB];
        short* hwr = &hlds[nb * HB];

        // prefetch next step's xp (overlaps MFMA)
        float xn[2][4];
        if (t + 1 < Tg) {
            const __hip_bfloat16* xprow = xp + ((size_t)(t + 1) * NBATCH + s0) * HID;
#pragma unroll
            for (int tau = 0; tau < 2; ++tau)
#pragma unroll
                for (int r = 0; r < 4; ++r)
                    xn[tau][r] = bf2f(xprow[(size_t)(q * 4 + r) * HID + colBase + tau * 16 + l15]);
        }

        f32x4 zz = {0.f, 0.f, 0.f, 0.f};
        f32x4 acc[2] = {zz, zz};
#pragma unroll
        for (int c = 0; c < 16; ++c) {
            bf16x8 a = *(const bf16x8*)&hrd[((c * 4 + q) * 16 + l15) * 8];
            acc[0] = __builtin_amdgcn_mfma_f32_16x16x32_bf16(a, bfr[0][c], acc[0], 0, 0, 0);
            acc[1] = __builtin_amdgcn_mfma_f32_16x16x32_bf16(a, bfr[1][c], acc[1], 0, 0, 0);
        }

        // h_{t+1}: tanh, write own cols to next LDS buf (+ out0 global)
#pragma unroll
        for (int tau = 0; tau < 2; ++tau)
#pragma unroll
            for (int r = 0; r < 4; ++r) {
                const int sl = q * 4 + r;
                const int j = colBase + tau * 16 + l15;
                float hnew = fast_tanh(acc[tau][r] + xv[tau][r]);
                float val = (t < len_r[r]) ? hnew : cur[tau][r];
                cur[tau][r] = val;
                unsigned short bits = f2bfbits(val);
                hwr[((j >> 3) * 16 + sl) * 8 + (j & 7)] = (short)bits;
                if (out0 && t < len_r[r])
                    out0[((size_t)t * NBATCH + s0 + sl) * HID + j] =
                        *reinterpret_cast<__hip_bfloat16*>(&bits);
            }
        __syncthreads();
#pragma unroll
        for (int tau = 0; tau < 2; ++tau)
#pragma unroll
            for (int r = 0; r < 4; ++r) xv[tau][r] = xn[tau][r];
    }

    // finals: h to d_out (output dtype) + bf16 copy for logits GEMM
#pragma unroll
    for (int tau = 0; tau < 2; ++tau)
#pragma unroll
        for (int r = 0; r < 4; ++r) {
            size_t idx = (size_t)(s0 + q * 4 + r) * HID + colBase + tau * 16 + l15;
            if (f32) ((float*)hout)[houtOff + idx] = cur[tau][r];
            else     ((__hip_bfloat16*)hout)[houtOff + idx] = f2bf(cur[tau][r]);
            hfbf[idx] = f2bf(cur[tau][r]);
        }
}

extern "C" void kernel_launch(void* const* d_in, const int* in_sizes, int n_in,
                              void* d_out, int out_size, void* d_ws, size_t ws_size,
                              hipStream_t stream) {
    const void* x    = d_in[0];
    const void* h0   = d_in[1];
    const int*  lens = (const int*)d_in[2];
    const void* Wih0 = d_in[3];
    const void* bih0 = d_in[4];
    const void* Whh0 = d_in[5];
    const void* bhh0 = d_in[6];
    const void* Wih1 = d_in[7];
    const void* bih1 = d_in[8];
    const void* Whh1 = d_in[9];
    const void* bhh1 = d_in[10];
    const void* Wfc  = d_in[11];
    const void* bfc  = d_in[12];

    const size_t MROWS = (size_t)T_STEPS * NBATCH;          // 65536
    size_t off = 0;
    auto take = [&](size_t bytes) { size_t o = off; off += (bytes + 255) & ~255ull; return o; };
    const size_t off_xp   = take(MROWS * HID * 2);          // 64 MB bf16
    const size_t off_out0 = take(MROWS * HID * 2);          // 64 MB bf16
    const size_t off_hfbf = take(2ull * NBATCH * HID * 2);
    const size_t off_dfl  = take(256);
    if (ws_size < off) return;  // workspace too small

    char* ws = (char*)d_ws;
    __hip_bfloat16* xp    = (__hip_bfloat16*)(ws + off_xp);
    __hip_bfloat16* out0  = (__hip_bfloat16*)(ws + off_out0);
    __hip_bfloat16* hfbf  = (__hip_bfloat16*)(ws + off_hfbf);
    unsigned int*   dflag = (unsigned int*)(ws + off_dfl);

    detect_dtype<<<1, 64, 0, stream>>>((const unsigned short*)x, dflag);

    // layer 0 input GEMM: xp0 = x @ Wih0^T + bih0 + bhh0
    gemm_bt64<<<dim3(HID / 64, MROWS / 64), 256, 0, stream>>>(
        x, Wih0, bih0, bhh0, xp, (int)MROWS, HID, INSZ, lens, dflag, 1, 0);
    // layer 0 recurrence (writes out0 + final h into d_out at elem 16384)
    rnn_recur<<<8, 1024, 0, stream>>>(
        xp, Whh0, h0, 0, lens, out0, d_out, NBATCH * 128, hfbf, dflag);
    // layer 1 input GEMM: xp1 = out0 @ Wih1^T + bih1 + bhh1 (reuse xp region)
    gemm_bt64<<<dim3(HID / 64, MROWS / 64), 256, 0, stream>>>(
        out0, Wih1, bih1, bhh1, xp, (int)MROWS, HID, HID, lens, dflag, 0, 0);
    // layer 1 recurrence (final h into d_out at elem 16384 + 65536)
    rnn_recur<<<8, 1024, 0, stream>>>(
        xp, Whh1, h0, 1, lens, nullptr, d_out,
        NBATCH * 128 + NBATCH * HID, hfbf + (size_t)NBATCH * HID, dflag);
    // logits = h1_final @ Wfc^T + bfc
    gemm_bt64<<<dim3(2, 2), 256, 0, stream>>>(
        hfbf + (size_t)NBATCH * HID, Wfc, bfc, nullptr,
        d_out, NBATCH, 128, HID, nullptr, dflag, 0, 1);
}

// Round 9
// 4914.940 us; speedup vs baseline: 1.6199x; 1.6199x over previous
//
#include <hip/hip_runtime.h>
#include <hip/hip_bf16.h>

// R9: layer-pipelined fused recurrence.
//   Stage 1: gemm_bt64 computes xp0 (as R5).
//   Stage 2: ONE fused kernel, 48 blocks x 512 thr:
//     blocks 0..15  = L0 recurrence (R5 core, 2 blocks/group). Publishes
//                     h_{t+1} (== out0[t]) as tagged u32 into a 64-deep ring
//                     [group][slot][16 samples][512 cols]; partner-half polls
//                     read the same ring. Back-pressure vs L1 every 8 steps.
//     blocks 16..47 = L1 recurrence (4 blocks/group, 128 cols each). Each wave
//                     holds Wih1+Whh1 frags for its 16 cols (128 AGPRs). xp1 is
//                     computed on the fly: A-frags polled DIRECTLY from the L0
//                     ring (8 contiguous tagged words); h-exchange 4-way via a
//                     2-slot tagged buffer. No xp1 GEMM, no out0 buffer.
//   Stage 3: logits GEMM from final h1.
//   All cross-block comms: relaxed agent-scope tagged stores + sc0 sc1 polls
//   (the R5-proven single path). Failsafe caps on every spin.

typedef __attribute__((ext_vector_type(8))) short bf16x8;
typedef __attribute__((ext_vector_type(4))) float f32x4;

#define T_STEPS 512
#define NBATCH  128
#define HID     512
#define INSZ    256
#define HB      8192    // shorts per LDS h buffer (16 samples x 512 cols, frag-major)
#define RING    64      // ring depth (steps); reuse guarded by l1prog
#define RWORDS  8192    // u32 per ring slot (16 samples x 512 cols)

static __device__ __forceinline__ float bf2f(__hip_bfloat16 v) { return __bfloat162float(v); }
static __device__ __forceinline__ __hip_bfloat16 f2bf(float v) { return __float2bfloat16(v); }

union BF8 { bf16x8 v; unsigned short u[8]; };
static __device__ __forceinline__ unsigned short f2bfbits(float x) {
    __hip_bfloat16 b = __float2bfloat16(x);
    return *reinterpret_cast<unsigned short*>(&b);
}
static __device__ __forceinline__ float loadE(const void* p, size_t i, bool f32) {
    return f32 ? ((const float*)p)[i] : bf2f(((const __hip_bfloat16*)p)[i]);
}
static __device__ __forceinline__ float fast_tanh(float x) {
    float e = __expf(2.f * x);
    float r = __builtin_amdgcn_rcpf(e + 1.f);
    return 1.f - 2.f * r;
}
static __device__ __forceinline__ void load2_l3(const unsigned int* p, uint4& a, uint4& b) {
    asm volatile("global_load_dwordx4 %0, %2, off sc0 sc1\n\t"
                 "global_load_dwordx4 %1, %3, off sc0 sc1\n\t"
                 "s_waitcnt vmcnt(0)"
                 : "=v"(a), "=v"(b) : "v"(p), "v"(p + 4) : "memory");
}
static __device__ __forceinline__ void load1_l3(const unsigned int* p, uint4& a) {
    asm volatile("global_load_dwordx4 %0, %1, off sc0 sc1\n\t"
                 "s_waitcnt vmcnt(0)"
                 : "=v"(a) : "v"(p) : "memory");
}
static __device__ __forceinline__ unsigned int loadw_l3(const unsigned int* p) {
    unsigned int v;
    asm volatile("global_load_dword %0, %1, off sc0 sc1\n\ts_waitcnt vmcnt(0)"
                 : "=v"(v) : "v"(p) : "memory");
    return v;
}

// ---------------- dtype probe
__global__ void detect_dtype(const unsigned short* __restrict__ x, unsigned int* __restrict__ dflag) {
    if (threadIdx.x == 0 && blockIdx.x == 0) {
        int sane = 0;
        for (int i = 0; i < 64; ++i) {
            unsigned short v = x[2 * i];
            unsigned int e = (v >> 7) & 0xFF;
            if (v == 0 || (e >= 0x60 && e <= 0x9F)) ++sane;
        }
        *dflag = (sane >= 48) ? 0u : 1u;
    }
}

// ---------------- GEMM: out[M][N] = A[M][K] @ W[N][K]^T + b1[N] (+ b2[N])
__global__ __launch_bounds__(256, 4) void gemm_bt64(
    const void* __restrict__ A, const void* __restrict__ W,
    const void* __restrict__ b1, const void* __restrict__ b2,
    void* __restrict__ out, int M, int N, int K,
    const int* __restrict__ lengths, const unsigned int* __restrict__ dflag,
    int aIsOrig, int outIsOutput)
{
    const int r0 = blockIdx.y * 64;
    if (lengths) {
        int t = r0 >> 7, n0 = r0 & 127;
        if (lengths[n0] <= t) return;
    }
    const bool f32 = *dflag != 0;
    const int c0 = blockIdx.x * 64;
    __shared__ short As[64 * 32];
    __shared__ short Bs[64 * 32];
    const int tid = threadIdx.x;
    const int lane = tid & 63, wave = tid >> 6;
    const int lrow = tid >> 2, lk = (tid & 3) * 8;
    const int q = (lane >> 4) & 3, l15 = lane & 15;

    f32x4 z = {0.f, 0.f, 0.f, 0.f};
    f32x4 acc[4];
#pragma unroll
    for (int m = 0; m < 4; ++m) acc[m] = z;

    for (int kk = 0; kk < K; kk += 32) {
        if (aIsOrig && f32) {
            const float* f = (const float*)A + (size_t)(r0 + lrow) * K + kk + lk;
            BF8 u;
#pragma unroll
            for (int i = 0; i < 8; ++i) u.u[i] = f2bfbits(f[i]);
            *(bf16x8*)&As[lrow * 32 + lk] = u.v;
        } else {
            *(bf16x8*)&As[lrow * 32 + lk] =
                *(const bf16x8*)((const __hip_bfloat16*)A + (size_t)(r0 + lrow) * K + kk + lk);
        }
        if (f32) {
            const float* f = (const float*)W + (size_t)(c0 + lrow) * K + kk + lk;
            BF8 u;
#pragma unroll
            for (int i = 0; i < 8; ++i) u.u[i] = f2bfbits(f[i]);
            *(bf16x8*)&Bs[lrow * 32 + lk] = u.v;
        } else {
            *(bf16x8*)&Bs[lrow * 32 + lk] =
                *(const bf16x8*)((const __hip_bfloat16*)W + (size_t)(c0 + lrow) * K + kk + lk);
        }
        __syncthreads();
        bf16x8 bfrag = *(const bf16x8*)&Bs[(wave * 16 + l15) * 32 + q * 8];
#pragma unroll
        for (int m = 0; m < 4; ++m) {
            bf16x8 afrag = *(const bf16x8*)&As[(m * 16 + l15) * 32 + q * 8];
            acc[m] = __builtin_amdgcn_mfma_f32_16x16x32_bf16(afrag, bfrag, acc[m], 0, 0, 0);
        }
        __syncthreads();
    }
    const int col = c0 + wave * 16 + l15;
    float bias = loadE(b1, col, f32) + (b2 ? loadE(b2, col, f32) : 0.f);
#pragma unroll
    for (int m = 0; m < 4; ++m) {
#pragma unroll
        for (int r = 0; r < 4; ++r) {
            int row = r0 + m * 16 + q * 4 + r;
            float v = acc[m][r] + bias;
            if (outIsOutput && f32) ((float*)out)[(size_t)row * N + col] = v;
            else ((__hip_bfloat16*)out)[(size_t)row * N + col] = f2bf(v);
        }
    }
}

// ---------------- fused 2-layer pipelined recurrence
__global__ __launch_bounds__(512, 2) void rnn_fused(
    const __hip_bfloat16* __restrict__ xp,    // [T*128][512] bf16 xp0
    const void* __restrict__ Whh0,            // [512][512] orig dtype
    const void* __restrict__ Wih1,            // [512][512] orig dtype
    const void* __restrict__ Whh1,            // [512][512] orig dtype
    const void* __restrict__ bih1,            // [512] orig dtype
    const void* __restrict__ bhh1,            // [512] orig dtype
    const void* __restrict__ h0all,           // [2][128][512] orig dtype
    const int* __restrict__ lengths,          // [128] sorted desc
    void* __restrict__ hout,                  // d_out; final h at elem 16384
    __hip_bfloat16* __restrict__ hfbf,        // [2][128][512] final h bf16
    unsigned int* __restrict__ ring,          // [8 gb][RING][16][512] u32 (L0 h / out0)
    unsigned int* __restrict__ l1ex,          // [8 gb][2][16][512] u32 (L1 h exchange)
    unsigned int* __restrict__ l1prog,        // [8] u32, memset 0 per launch
    const unsigned int* __restrict__ dflag)
{
    const int tid = threadIdx.x, lane = tid & 63, wave = tid >> 6;
    const int q = (lane >> 4) & 3, l15 = lane & 15;
    const bool f32 = *dflag != 0;
    __shared__ short hlds[2 * HB];

    if (blockIdx.x < 16) {
        // ================= L0: R5 core with 64-ring publish =================
        const int gb = blockIdx.x & 7, p = (blockIdx.x >> 3) & 1;
        const int colBase = p * 256 + wave * 32;
        const int s0 = gb * 16;
        const int pcPart = (1 - p) * 256;

        bf16x8 bfr[2][16];
#pragma unroll
        for (int tau = 0; tau < 2; ++tau)
#pragma unroll
            for (int c = 0; c < 16; ++c) {
                if (f32) {
                    const float* f = (const float*)Whh0 + (size_t)(colBase + tau * 16 + l15) * HID + c * 32 + q * 8;
                    BF8 u;
#pragma unroll
                    for (int i = 0; i < 8; ++i) u.u[i] = f2bfbits(f[i]);
                    bfr[tau][c] = u.v;
                } else {
                    bfr[tau][c] = *(const bf16x8*)((const __hip_bfloat16*)Whh0 +
                        (size_t)(colBase + tau * 16 + l15) * HID + c * 32 + q * 8);
                }
            }

        int len_r[4];
#pragma unroll
        for (int r = 0; r < 4; ++r) len_r[r] = lengths[s0 + q * 4 + r];

        float cur[2][4];
#pragma unroll
        for (int tau = 0; tau < 2; ++tau)
#pragma unroll
            for (int r = 0; r < 4; ++r)
                cur[tau][r] = loadE(h0all, (size_t)(s0 + q * 4 + r) * HID + colBase + tau * 16 + l15, f32);

        {   // stage S_0 (frag-major)
            const int sr = tid >> 5, cb16 = (tid & 31) * 16;
            BF8 u0, u1;
#pragma unroll
            for (int i = 0; i < 8; ++i) {
                u0.u[i] = f2bfbits(loadE(h0all, (size_t)(s0 + sr) * HID + cb16 + i, f32));
                u1.u[i] = f2bfbits(loadE(h0all, (size_t)(s0 + sr) * HID + cb16 + 8 + i, f32));
            }
            *(bf16x8*)&hlds[(((cb16 >> 3) * 16) + sr) * 8] = u0.v;
            *(bf16x8*)&hlds[((((cb16 + 8) >> 3) * 16) + sr) * 8] = u1.v;
        }
        __syncthreads();

        const int Tg = lengths[s0];
        unsigned int* rg = ring + (size_t)gb * RING * RWORDS;

        float xv[2][4];
        {
            const __hip_bfloat16* xprow = xp + (size_t)s0 * HID;
#pragma unroll
            for (int tau = 0; tau < 2; ++tau)
#pragma unroll
                for (int r = 0; r < 4; ++r)
                    xv[tau][r] = bf2f(xprow[(size_t)(q * 4 + r) * HID + colBase + tau * 16 + l15]);
        }

        for (int t = 0; t < Tg; ++t) {
            const int cb_ = t & 1, nb = (t + 1) & 1;
            const int slot = (t + 1) & (RING - 1);
            const short* hrd = &hlds[cb_ * HB];
            short* hwr = &hlds[nb * HB];

            // ring-reuse back-pressure vs L1 (every 8 steps)
            if ((t & 7) == 0 && t >= RING - 8) {
                const unsigned int* pw = &l1prog[gb];
                int spins = 0;
                while ((int)loadw_l3(pw) < t - 56) {
                    if (++spins > 64) __builtin_amdgcn_s_sleep(2);
                    if (spins > (1 << 24)) break;
                }
            }

            float xn[2][4];
            if (t + 1 < Tg) {
                const __hip_bfloat16* xprow = xp + ((size_t)(t + 1) * NBATCH + s0) * HID;
#pragma unroll
                for (int tau = 0; tau < 2; ++tau)
#pragma unroll
                    for (int r = 0; r < 4; ++r)
                        xn[tau][r] = bf2f(xprow[(size_t)(q * 4 + r) * HID + colBase + tau * 16 + l15]);
            }

            f32x4 zz = {0.f, 0.f, 0.f, 0.f};
            f32x4 acc[2] = {zz, zz};
#pragma unroll
            for (int c = 0; c < 16; ++c) {
                bf16x8 a = *(const bf16x8*)&hrd[((c * 4 + q) * 16 + l15) * 8];
                acc[0] = __builtin_amdgcn_mfma_f32_16x16x32_bf16(a, bfr[0][c], acc[0], 0, 0, 0);
                acc[1] = __builtin_amdgcn_mfma_f32_16x16x32_bf16(a, bfr[1][c], acc[1], 0, 0, 0);
            }

            const unsigned int tag = (unsigned int)(t + 1);
            unsigned int* rw = rg + (size_t)slot * RWORDS;
            unsigned short bits[2][4];
#pragma unroll
            for (int tau = 0; tau < 2; ++tau)
#pragma unroll
                for (int r = 0; r < 4; ++r) {
                    float hnew = fast_tanh(acc[tau][r] + xv[tau][r]);
                    float val = (t < len_r[r]) ? hnew : cur[tau][r];
                    cur[tau][r] = val;
                    bits[tau][r] = f2bfbits(val);
                    __hip_atomic_store(&rw[(q * 4 + r) * 512 + colBase + tau * 16 + l15],
                                       (tag << 16) | (unsigned int)bits[tau][r],
                                       __ATOMIC_RELAXED, __HIP_MEMORY_SCOPE_AGENT);
                }
#pragma unroll
            for (int tau = 0; tau < 2; ++tau)
#pragma unroll
                for (int r = 0; r < 4; ++r) {
                    const int sl = q * 4 + r;
                    const int j = colBase + tau * 16 + l15;
                    hwr[((j >> 3) * 16 + sl) * 8 + (j & 7)] = (short)bits[tau][r];
                }

            if (t + 1 < Tg) {   // poll partner half from ring
                const unsigned int* exr = rw + (tid >> 5) * 512 + pcPart + (tid & 31) * 8;
                uint4 va, vb;
                int spins = 0;
                for (;;) {
                    load2_l3(exr, va, vb);
                    bool ok = (va.x >> 16) == tag && (va.y >> 16) == tag &&
                              (va.z >> 16) == tag && (va.w >> 16) == tag &&
                              (vb.x >> 16) == tag && (vb.y >> 16) == tag &&
                              (vb.z >> 16) == tag && (vb.w >> 16) == tag;
                    if (ok) break;
                    if (++spins > 4) __builtin_amdgcn_s_sleep(1);
                    if (spins > (1 << 24)) break;
                }
                BF8 u;
                u.u[0] = (unsigned short)va.x; u.u[1] = (unsigned short)va.y;
                u.u[2] = (unsigned short)va.z; u.u[3] = (unsigned short)va.w;
                u.u[4] = (unsigned short)vb.x; u.u[5] = (unsigned short)vb.y;
                u.u[6] = (unsigned short)vb.z; u.u[7] = (unsigned short)vb.w;
                const int jp = pcPart + (tid & 31) * 8;
                *(bf16x8*)&hwr[((jp >> 3) * 16 + (tid >> 5)) * 8] = u.v;
            }
            __syncthreads();
#pragma unroll
            for (int tau = 0; tau < 2; ++tau)
#pragma unroll
                for (int r = 0; r < 4; ++r) xv[tau][r] = xn[tau][r];
        }

#pragma unroll
        for (int tau = 0; tau < 2; ++tau)
#pragma unroll
            for (int r = 0; r < 4; ++r) {
                size_t idx = (size_t)(s0 + q * 4 + r) * HID + colBase + tau * 16 + l15;
                if (f32) ((float*)hout)[NBATCH * 128 + idx] = cur[tau][r];
                else     ((__hip_bfloat16*)hout)[NBATCH * 128 + idx] = f2bf(cur[tau][r]);
                hfbf[idx] = f2bf(cur[tau][r]);
            }
    } else {
        // ================= L1: 4 blocks/group, fused xp1 =================
        const int idx1 = blockIdx.x - 16;
        const int gb = idx1 & 7, q4 = (idx1 >> 3) & 3;
        const int s0 = gb * 16;
        const int colW = q4 * 128 + wave * 16;   // this wave's 16 output columns
        const int mycol = colW + l15;

        // B fragments: Whh1 + Wih1 for the wave's 16 cols (64+64 regs)
        bf16x8 bfrH[16], bfrX[16];
#pragma unroll
        for (int c = 0; c < 16; ++c) {
            if (f32) {
                const float* fh = (const float*)Whh1 + (size_t)mycol * HID + c * 32 + q * 8;
                const float* fx = (const float*)Wih1 + (size_t)mycol * HID + c * 32 + q * 8;
                BF8 uh, ux;
#pragma unroll
                for (int i = 0; i < 8; ++i) { uh.u[i] = f2bfbits(fh[i]); ux.u[i] = f2bfbits(fx[i]); }
                bfrH[c] = uh.v; bfrX[c] = ux.v;
            } else {
                bfrH[c] = *(const bf16x8*)((const __hip_bfloat16*)Whh1 + (size_t)mycol * HID + c * 32 + q * 8);
                bfrX[c] = *(const bf16x8*)((const __hip_bfloat16*)Wih1 + (size_t)mycol * HID + c * 32 + q * 8);
            }
        }
        const float xb = loadE(bih1, mycol, f32) + loadE(bhh1, mycol, f32);

        int len_r[4];
#pragma unroll
        for (int r = 0; r < 4; ++r) len_r[r] = lengths[s0 + q * 4 + r];
        const int lenA = lengths[s0 + l15];   // row mask for ring A-frag polls

        float cur[4];
#pragma unroll
        for (int r = 0; r < 4; ++r)
            cur[r] = loadE(h0all, (size_t)NBATCH * HID + (size_t)(s0 + q * 4 + r) * HID + mycol, f32);

        {   // stage S_0 of h1 (frag-major)
            const int sr = tid >> 5, cb16 = (tid & 31) * 16;
            const size_t base = (size_t)NBATCH * HID + (size_t)(s0 + sr) * HID + cb16;
            BF8 u0, u1;
#pragma unroll
            for (int i = 0; i < 8; ++i) {
                u0.u[i] = f2bfbits(loadE(h0all, base + i, f32));
                u1.u[i] = f2bfbits(loadE(h0all, base + 8 + i, f32));
            }
            *(bf16x8*)&hlds[(((cb16 >> 3) * 16) + sr) * 8] = u0.v;
            *(bf16x8*)&hlds[((((cb16 + 8) >> 3) * 16) + sr) * 8] = u1.v;
        }
        __syncthreads();

        const int Tg = lengths[s0];
        const unsigned int* rg = ring + (size_t)gb * RING * RWORDS;
        unsigned int* exg = l1ex + (size_t)gb * 2 * RWORDS;

        for (int t = 0; t < Tg; ++t) {
            const int cb_ = t & 1, nb = (t + 1) & 1;
            const int slot = (t + 1) & (RING - 1);
            const short* hrd = &hlds[cb_ * HB];
            short* hwr = &hlds[nb * HB];
            const unsigned int tag = (unsigned int)(t + 1);

            f32x4 acc = {0.f, 0.f, 0.f, 0.f};

            // xp1 contribution: A-frags (out0[t] rows) polled straight from ring.
            // Lane's A row = sample l15; skip poll for finished rows (value unused).
            const unsigned int* rbase = rg + (size_t)slot * RWORDS + l15 * 512;
            const bool rowLive = (t < lenA);
#pragma unroll
            for (int c = 0; c < 16; ++c) {
                BF8 u;
                if (rowLive) {
                    const unsigned int* pa = rbase + c * 32 + q * 8;
                    uint4 va, vb;
                    int spins = 0;
                    for (;;) {
                        load2_l3(pa, va, vb);
                        bool ok = (va.x >> 16) == tag && (va.y >> 16) == tag &&
                                  (va.z >> 16) == tag && (va.w >> 16) == tag &&
                                  (vb.x >> 16) == tag && (vb.y >> 16) == tag &&
                                  (vb.z >> 16) == tag && (vb.w >> 16) == tag;
                        if (ok) break;
                        if (++spins > 8) __builtin_amdgcn_s_sleep(1);
                        if (spins > (1 << 24)) break;
                    }
                    u.u[0] = (unsigned short)va.x; u.u[1] = (unsigned short)va.y;
                    u.u[2] = (unsigned short)va.z; u.u[3] = (unsigned short)va.w;
                    u.u[4] = (unsigned short)vb.x; u.u[5] = (unsigned short)vb.y;
                    u.u[6] = (unsigned short)vb.z; u.u[7] = (unsigned short)vb.w;
                } else {
#pragma unroll
                    for (int i = 0; i < 8; ++i) u.u[i] = 0;
                }
                acc = __builtin_amdgcn_mfma_f32_16x16x32_bf16(u.v, bfrX[c], acc, 0, 0, 0);
            }
            // h contribution
#pragma unroll
            for (int c = 0; c < 16; ++c) {
                bf16x8 a = *(const bf16x8*)&hrd[((c * 4 + q) * 16 + l15) * 8];
                acc = __builtin_amdgcn_mfma_f32_16x16x32_bf16(a, bfrH[c], acc, 0, 0, 0);
            }

            // h1_{t+1}: publish own 16 cols, LDS own, poll 3 partners
            unsigned int* exw = exg + (size_t)nb * RWORDS;
            unsigned short bits[4];
#pragma unroll
            for (int r = 0; r < 4; ++r) {
                float hnew = fast_tanh(acc[r] + xb);
                float val = (t < len_r[r]) ? hnew : cur[r];
                cur[r] = val;
                bits[r] = f2bfbits(val);
                __hip_atomic_store(&exw[(q * 4 + r) * 512 + mycol],
                                   (tag << 16) | (unsigned int)bits[r],
                                   __ATOMIC_RELAXED, __HIP_MEMORY_SCOPE_AGENT);
            }
#pragma unroll
            for (int r = 0; r < 4; ++r) {
                const int sl = q * 4 + r;
                hwr[((mycol >> 3) * 16 + sl) * 8 + (mycol & 7)] = (short)bits[r];
            }

            if (t + 1 < Tg) {
                const int sr = tid >> 5, cw = (tid & 31) * 4;  // 4 cols per thread per partner
#pragma unroll
                for (int o = 1; o < 4; ++o) {
                    const int q4p = (q4 + o) & 3;
                    const int j0 = q4p * 128 + cw;
                    const unsigned int* pp = exw + sr * 512 + j0;
                    uint4 va;
                    int spins = 0;
                    for (;;) {
                        load1_l3(pp, va);
                        bool ok = (va.x >> 16) == tag && (va.y >> 16) == tag &&
                                  (va.z >> 16) == tag && (va.w >> 16) == tag;
                        if (ok) break;
                        if (++spins > 4) __builtin_amdgcn_s_sleep(1);
                        if (spins > (1 << 24)) break;
                    }
                    unsigned short w[4] = {(unsigned short)va.x, (unsigned short)va.y,
                                           (unsigned short)va.z, (unsigned short)va.w};
                    short* d = &hwr[((j0 >> 3) * 16 + sr) * 8 + (j0 & 7)];
                    d[0] = (short)w[0]; d[1] = (short)w[1]; d[2] = (short)w[2]; d[3] = (short)w[3];
                }
            }
            if (q4 == 0 && tid == 0)
                __hip_atomic_store(&l1prog[gb], (unsigned int)(t + 1),
                                   __ATOMIC_RELAXED, __HIP_MEMORY_SCOPE_AGENT);
            __syncthreads();
        }

#pragma unroll
        for (int r = 0; r < 4; ++r) {
            size_t idx = (size_t)(s0 + q * 4 + r) * HID + mycol;
            if (f32) ((float*)hout)[NBATCH * 128 + NBATCH * HID + idx] = cur[r];
            else     ((__hip_bfloat16*)hout)[NBATCH * 128 + NBATCH * HID + idx] = f2bf(cur[r]);
            hfbf[(size_t)NBATCH * HID + idx] = f2bf(cur[r]);
        }
    }
}

extern "C" void kernel_launch(void* const* d_in, const int* in_sizes, int n_in,
                              void* d_out, int out_size, void* d_ws, size_t ws_size,
                              hipStream_t stream) {
    const void* x    = d_in[0];
    const void* h0   = d_in[1];
    const int*  lens = (const int*)d_in[2];
    const void* Wih0 = d_in[3];
    const void* bih0 = d_in[4];
    const void* Whh0 = d_in[5];
    const void* bhh0 = d_in[6];
    const void* Wih1 = d_in[7];
    const void* bih1 = d_in[8];
    const void* Whh1 = d_in[9];
    const void* bhh1 = d_in[10];
    const void* Wfc  = d_in[11];
    const void* bfc  = d_in[12];

    const size_t MROWS = (size_t)T_STEPS * NBATCH;
    size_t off = 0;
    auto take = [&](size_t bytes) { size_t o = off; off += (bytes + 255) & ~255ull; return o; };
    const size_t off_xp   = take(MROWS * HID * 2);                 // 64 MB
    const size_t off_ring = take(8ull * RING * RWORDS * 4);        // 16 MB
    const size_t off_l1ex = take(8ull * 2 * RWORDS * 4);           // 512 KB
    const size_t off_ctl  = take(4096);                            // l1prog + pad
    const size_t off_hfbf = take(2ull * NBATCH * HID * 2);
    const size_t off_dfl  = take(256);
    if (ws_size < off) return;

    char* ws = (char*)d_ws;
    __hip_bfloat16* xp    = (__hip_bfloat16*)(ws + off_xp);
    unsigned int*   ring  = (unsigned int*)(ws + off_ring);
    unsigned int*   l1ex  = (unsigned int*)(ws + off_l1ex);
    unsigned int*   ctl   = (unsigned int*)(ws + off_ctl);
    __hip_bfloat16* hfbf  = (__hip_bfloat16*)(ws + off_hfbf);
    unsigned int*   dflag = (unsigned int*)(ws + off_dfl);

    detect_dtype<<<1, 64, 0, stream>>>((const unsigned short*)x, dflag);
    hipMemsetAsync(ctl, 0, 4096, stream);   // l1prog = 0 (ring/l1ex tags self-validate vs poison)

    // xp0 = x @ Wih0^T + bih0 + bhh0
    gemm_bt64<<<dim3(HID / 64, MROWS / 64), 256, 0, stream>>>(
        x, Wih0, bih0, bhh0, xp, (int)MROWS, HID, INSZ, lens, dflag, 1, 0);
    // fused pipelined recurrence (L0 + L1)
    rnn_fused<<<48, 512, 0, stream>>>(
        xp, Whh0, Wih1, Whh1, bih1, bhh1, h0, lens,
        d_out, hfbf, ring, l1ex, ctl, dflag);
    // logits = h1_final @ Wfc^T + bfc
    gemm_bt64<<<dim3(2, 2), 256, 0, stream>>>(
        hfbf + (size_t)NBATCH * HID, Wfc, bfc, nullptr,
        d_out, NBATCH, 128, HID, nullptr, dflag, 0, 1);
}